// Round 14
// baseline (117.756 us; speedup 1.0000x reference)
//
#include <hip/hip_runtime.h>
#include <math.h>

#define B 8
#define T 128
#define NKEY 127   // t-1
#define NPAD 128   // padded key count (score row 127 forced to prob 0)
#define KDIM 64    // Q_DIM == KV_DIM
#define NH 4       // heads
#define CH 256     // NH*KDIM output channels
#define LAM 2.885390081777927f   // 2*log2(e): e^{2x} = exp2(LAM*x)

typedef _Float16 half8v __attribute__((ext_vector_type(8)));  // 8 fp16 (4 VGPRs)
typedef _Float16 half4v __attribute__((ext_vector_type(4)));  // 4 fp16 (b64)
typedef float floatx4 __attribute__((ext_vector_type(4)));    // MFMA C/D

// 8x float -> fp16 RNE. Verified (R15/R17/R18 pass): absmax <= 9.77e-4.
__device__ __forceinline__ half8v cvt8_rne(const float4& a, const float4& b) {
    half8v h;
    h[0] = (_Float16)a.x; h[1] = (_Float16)a.y;
    h[2] = (_Float16)a.z; h[3] = (_Float16)a.w;
    h[4] = (_Float16)b.x; h[5] = (_Float16)b.y;
    h[6] = (_Float16)b.z; h[7] = (_Float16)b.w;
    return h;
}

// R21 = R18 + ONE technique applied twice: COALESCED weight-row reads.
// Falsified: occupancy (R9/R10/R16), epilogue VALU (R18), staging latency
// (R19), score-loop ILP (R20). Remaining unexplained stall mass (~70% of
// cycles, no wave issuing): L1 transaction serialization. Old Wq pass and
// Phase C read one 256B-strided row per thread -> each float4 instruction
// touches 64 DISTINCT cache lines; 16 instr x 64 lines x 2 phases x 16
// waves/CU ~ 33K cycles of L1 serialization per CU. Fix: flat-coalesced
// read W.flat[i*1024 + t*4] (16 lines/instr, 4x fewer transactions); the
// float4 is row i*16+(t>>4), k-chunk (t&15)*4; 4x shfl_xor reduce across
// the 16 cols sharing a row; col 0 writes. Phase C: head = i>>2 is wave-
// uniform; wkv LDS read broadcast/2-way (free); +1 barrier (wkv now read
// cross-wave). Everything else byte-identical to R18.
__global__ __launch_bounds__(256, 2)
void attn_kernel(const float* __restrict__ q_x,   // (B,T,64)
                 const float* __restrict__ kv_x,  // (B,T,127,64)
                 const float* __restrict__ Wk,    // (256,64)
                 const float* __restrict__ Wq,    // (256,64)
                 const float* __restrict__ Wv,    // (256,64)
                 const float* __restrict__ bias,  // (64,)
                 const float* __restrict__ Ws,    // (1,64)
                 const float* __restrict__ bs,    // (1,) -- cancels in softmax
                 float* __restrict__ out)         // (B,T,256)
{
    __shared__ __align__(16) _Float16 frag[16][64][8];   // 16 KB: fp16 B-frags
    __shared__ __align__(16) _Float16 kvT[64][132];      // 16.5 KB: fp16 kv^T
    __shared__ float qb_lds[CH];                         // 1 KB: LAM*(query+bias)
    __shared__ float p_lds[NH][NPAD];                    // 2 KB: scores then probs
    __shared__ __align__(16) float wkv_lds[NH][KDIM];    // 1 KB -> total 37376 B

    const int bt   = blockIdx.x;
    const int tid  = threadIdx.x;
    const int h    = tid >> 6;    // wave index == head index
    const int lane = tid & 63;
    const int col  = lane & 15;   // MFMA n/m lane index
    const int quad = lane >> 4;   // MFMA k-group / row-group

    const float* __restrict__ kvg = kv_x + (size_t)bt * NKEY * KDIM;

    // ---- convert kv (global) -> fragment-ordered fp16 LDS + fp16 kv^T ----
    // chunk = nt*2+ks; frag write addr = chunk*1024 + lane*16: lane-linear.
    // Fragment content: kv[nt*16 + (lane&15)][ks*32 + (lane>>4)*8 + j]
    #pragma unroll
    for (int w = 0; w < 4; ++w) {
        const int chunk = w * 4 + h;          // each wave does 4 chunks
        const int nt = chunk >> 1, ks = chunk & 1;
        const int n  = nt * 16 + (lane & 15);
        const int k0 = ks * 32 + (lane >> 4) * 8;
        float4 a = make_float4(0.f, 0.f, 0.f, 0.f);
        float4 b = make_float4(0.f, 0.f, 0.f, 0.f);
        if (n < NKEY) {
            const float* p = kvg + (size_t)n * KDIM + k0;
            a = *(const float4*)p;
            b = *(const float4*)(p + 4);
        }
        half8v hv = cvt8_rne(a, b);
        *(half8v*)&frag[chunk][lane][0] = hv;
        #pragma unroll
        for (int j = 0; j < 8; ++j)           // transpose: rows k0..k0+7, col n
            kvT[k0 + j][n] = hv[j];           // zeros land in column 127
    }

    // ---- query+bias, COALESCED: thread t reads Wq.flat[i*1024 + t*4] ----
    // That float4 = Wq[row][kc..kc+3], row = i*16 + (t>>4), kc = (t&15)*4.
    // Per instr: consecutive lanes -> consecutive 16B = 16 lines (was 64).
    // The 16 lanes sharing a row are quad-group g = t>>4 (in-wave, col 0..15):
    // 4x shfl_xor reduces; col 0 writes qb_lds[row] = LAM*(dot + bias).
    {
        const int g  = tid >> 4;              // row group (wave*4 + quad)
        const int kc = (tid & 15) * 4;
        const float4 q4 = *(const float4*)(q_x + (size_t)bt * KDIM + kc);
        #pragma unroll
        for (int i = 0; i < 16; ++i) {
            float4 w = *(const float4*)(Wq + i * 1024 + tid * 4);
            float s = fmaf(q4.x, w.x, fmaf(q4.y, w.y,
                      fmaf(q4.z, w.z, q4.w * w.w)));
            s += __shfl_xor(s, 1, 64);
            s += __shfl_xor(s, 2, 64);
            s += __shfl_xor(s, 4, 64);
            s += __shfl_xor(s, 8, 64);
            const int row = i * 16 + g;
            if (col == 0)
                qb_lds[row] = (s + bias[row & 63]) * LAM;
        }
    }

    // ---- A-fragments: LAM*Wk rows of this head, fp16 RNE ----
    // lane holds LAM*Wk[h*64 + jt*16 + col][ks*32 + quad*8 + j]
    half8v ah[4][2];
    #pragma unroll
    for (int jt = 0; jt < 4; ++jt)
        #pragma unroll
        for (int ks = 0; ks < 2; ++ks) {
            const float* wrow = Wk + (size_t)(h * 64 + jt * 16 + col) * KDIM
                                   + ks * 32 + quad * 8;
            float4 a = *(const float4*)wrow;
            float4 b = *(const float4*)(wrow + 4);
            a.x *= LAM; a.y *= LAM; a.z *= LAM; a.w *= LAM;
            b.x *= LAM; b.y *= LAM; b.z *= LAM; b.w *= LAM;
            ah[jt][ks] = cvt8_rne(a, b);
        }

    __syncthreads();   // B1: frags + kvT + qb ready

    // ---- qb as MFMA C-init; folded ws; hoisted wssum (R18-verified) ----
    // C/D layout: col = lane&15 = n, row = quad*4 + r = j in jt-tile.
    floatx4 qb4[4];
    float   ws2[4][4];
    float   wssum = 0.f;
    #pragma unroll
    for (int jt = 0; jt < 4; ++jt) {
        qb4[jt] = *(const floatx4*)&qb_lds[h * 64 + jt * 16 + quad * 4];
        #pragma unroll
        for (int r = 0; r < 4; ++r) {
            float w = Ws[jt * 16 + quad * 4 + r];
            wssum += w;
            ws2[jt][r] = -2.f * w;
        }
    }

    // ---- scores: 8 n-tiles of 16 keys; single-pass fp16 MFMA ----
    #pragma unroll
    for (int nt = 0; nt < 8; ++nt) {
        half8v b0 = *(const half8v*)&frag[nt * 2 + 0][lane][0];
        half8v b1 = *(const half8v*)&frag[nt * 2 + 1][lane][0];

        floatx4 acc[4];
        #pragma unroll
        for (int jt = 0; jt < 4; ++jt) {
            floatx4 c = qb4[jt];   // C-init = LAM*(query+bias); keys add on
            c = __builtin_amdgcn_mfma_f32_16x16x32_f16(ah[jt][0], b0, c, 0, 0, 0);
            c = __builtin_amdgcn_mfma_f32_16x16x32_f16(ah[jt][1], b1, c, 0, 0, 0);
            acc[jt] = c;
        }

        // epilogue: score[n] = wssum + sum_j ws2[j] * 1/(exp2(c)+1)
        //   (ws*tanh(x) = ws - 2ws/(e^{2x}+1), c = LAM*x, exp2(c) = e^{2x})
        float partial = wssum;
        #pragma unroll
        for (int jt = 0; jt < 4; ++jt)
            #pragma unroll
            for (int r = 0; r < 4; ++r) {
                float e  = exp2f(acc[jt][r]);               // v_exp_f32
                float rc = __builtin_amdgcn_rcpf(e + 1.f);
                partial  = fmaf(ws2[jt][r], rc, partial);
            }
        partial += __shfl_xor(partial, 16, 64);   // reduce across quads (same col)
        partial += __shfl_xor(partial, 32, 64);
        if (lane < 16) p_lds[h][nt * 16 + lane] = partial;
    }
    // no barrier: wave h is sole writer+reader of p_lds[h][*] (DS in-order)

    // ---- softmax over the 127 real keys (2 scores per lane) ----
    float invl;
    {
        float s_a = p_lds[h][lane];
        float s_b = p_lds[h][64 + lane];
        if (lane == 63) s_b = -1e30f;          // mask pad row 127
        float mx = fmaxf(s_a, s_b);
        #pragma unroll
        for (int off = 32; off > 0; off >>= 1)
            mx = fmaxf(mx, __shfl_xor(mx, off, 64));
        float pa = __expf(s_a - mx);
        float pb = __expf(s_b - mx);           // lane 63 -> 0
        float ls = pa + pb;
        #pragma unroll
        for (int off = 32; off > 0; off >>= 1)
            ls += __shfl_xor(ls, off, 64);
        invl = 1.f / ls;
        p_lds[h][lane]      = pa;              // unnormalized probs
        p_lds[h][64 + lane] = pb;              // p_lds[h][127] = 0 masks pad
    }

    // ---- Phase B: wkv[h][k=lane] = (sum_n p[n] * kvT[k][n]) / l, all LDS ----
    // 32 linear ds_read_b64 of row k (stride 264 B == 2 dw mod 32: lanes
    // k,k+16 alias 2-way = free; k,k+8 differ by 16 banks). Probs: float4
    // uniform broadcast. Column 127 holds zeros; p[127] = 0 too.
    {
        const _Float16* kvr = &kvT[lane][0];
        float w0 = 0.f, w1 = 0.f, w2 = 0.f, w3 = 0.f;
        #pragma unroll 8
        for (int s = 0; s < 32; ++s) {
            half4v v  = *(const half4v*)(kvr + s * 4);
            float4 p4 = *(const float4*)&p_lds[h][s * 4];    // uniform broadcast
            w0 = fmaf(p4.x, (float)v[0], w0);
            w1 = fmaf(p4.y, (float)v[1], w1);
            w2 = fmaf(p4.z, (float)v[2], w2);
            w3 = fmaf(p4.w, (float)v[3], w3);
        }
        wkv_lds[h][lane] = ((w0 + w1) + (w2 + w3)) * invl;
    }

    __syncthreads();   // B2: wkv of ALL heads visible (Phase C reads cross-head)

    // ---- Phase C, COALESCED: thread t reads Wv.flat[i*1024 + t*4] ----
    // float4 = Wv[row][kc..kc+3], row = i*16 + (t>>4), kc = (t&15)*4;
    // head of row = i>>2 (wave-uniform per i). wkv LDS read: quads broadcast,
    // cols 2-way = free. 4x shfl_xor reduce across cols; col 0 stores out[row].
    {
        const int g  = tid >> 4;
        const int kc = (tid & 15) * 4;
        #pragma unroll
        for (int i = 0; i < 16; ++i) {
            float4 w = *(const float4*)(Wv + i * 1024 + tid * 4);
            float4 v = *(const float4*)&wkv_lds[i >> 2][kc];
            float s = fmaf(v.x, w.x, fmaf(v.y, w.y,
                      fmaf(v.z, w.z, v.w * w.w)));
            s += __shfl_xor(s, 1, 64);
            s += __shfl_xor(s, 2, 64);
            s += __shfl_xor(s, 4, 64);
            s += __shfl_xor(s, 8, 64);
            if (col == 0)
                out[(size_t)bt * CH + i * 16 + g] = s;
        }
    }
}

extern "C" void kernel_launch(void* const* d_in, const int* in_sizes, int n_in,
                              void* d_out, int out_size, void* d_ws, size_t ws_size,
                              hipStream_t stream) {
    const float* q_x  = (const float*)d_in[0];
    const float* kv_x = (const float*)d_in[1];
    const float* Wk   = (const float*)d_in[2];
    const float* Wq   = (const float*)d_in[3];
    const float* Wv   = (const float*)d_in[4];
    const float* bias = (const float*)d_in[5];
    const float* Ws   = (const float*)d_in[6];
    const float* bs   = (const float*)d_in[7];
    float* out = (float*)d_out;

    attn_kernel<<<dim3(B * T), dim3(256), 0, stream>>>(
        q_x, kv_x, Wk, Wq, Wv, bias, Ws, bs, out);
}

// Round 15
// 114.867 us; speedup vs baseline: 1.0252x; 1.0252x over previous
//
#include <hip/hip_runtime.h>
#include <math.h>

#define B 8
#define T 128
#define NKEY 127   // t-1
#define NPAD 128   // padded key count (score row 127 forced to prob 0)
#define KDIM 64    // Q_DIM == KV_DIM
#define NH 4       // heads
#define CH 256     // NH*KDIM output channels

typedef _Float16 half8v __attribute__((ext_vector_type(8)));  // 8 fp16 (4 VGPRs)
typedef _Float16 half4v __attribute__((ext_vector_type(4)));  // 4 fp16 (b64)
typedef float floatx4 __attribute__((ext_vector_type(4)));    // MFMA C/D

// tanh(x) = 1 - 2/(e^{2x}+1). Saturates correctly at +/-inf, no clamp needed.
__device__ __forceinline__ float fast_tanh(float x) {
    float e = __expf(2.f * x);
    float r = __builtin_amdgcn_rcpf(e + 1.f);
    return fmaf(-2.f, r, 1.f);
}

// 8x float -> fp16 RNE. Verified (R15/R17 pass): absmax <= 9.77e-4.
__device__ __forceinline__ half8v cvt8_rne(const float4& a, const float4& b) {
    half8v h;
    h[0] = (_Float16)a.x; h[1] = (_Float16)a.y;
    h[2] = (_Float16)a.z; h[3] = (_Float16)a.w;
    h[4] = (_Float16)b.x; h[5] = (_Float16)b.y;
    h[6] = (_Float16)b.z; h[7] = (_Float16)b.w;
    return h;
}

// R22 = R17 champion (113.5us harness, PASSED) + ONE delta: T5 s_setprio(1)
// around the score-phase MFMA cluster.
// Falsified single-resource theories: occupancy (R9/R10/R16), epilogue VALU
// (R18), staging latency (R19), score-loop ILP (R20), memory transactions
// (R21: FETCH 25.5->17.3 MB, time unchanged). Dispatch pinned at 40-46us
// across every shape; all pipes <35%. T5's documented regime (m191: +4-7% on
// attn, 0% on lockstep GEMM) matches our CU state: 4 independent blocks/CU
// with large finish-skew (avg occ 33% vs 50% cap), MFMA bursts interleaved
// with long trans/VALU phases -- the scheduler has something to arbitrate.
// If neutral: structural floor declared next round.
__global__ __launch_bounds__(256, 2)
void attn_kernel(const float* __restrict__ q_x,   // (B,T,64)
                 const float* __restrict__ kv_x,  // (B,T,127,64)
                 const float* __restrict__ Wk,    // (256,64)
                 const float* __restrict__ Wq,    // (256,64)
                 const float* __restrict__ Wv,    // (256,64)
                 const float* __restrict__ bias,  // (64,)
                 const float* __restrict__ Ws,    // (1,64)
                 const float* __restrict__ bs,    // (1,) -- cancels in softmax
                 float* __restrict__ out)         // (B,T,256)
{
    __shared__ __align__(16) _Float16 frag[16][64][8];   // 16 KB: fp16 B-frags
    __shared__ __align__(16) _Float16 kvT[64][132];      // 16.5 KB: fp16 kv^T
    __shared__ float qb_lds[CH];                         // 1 KB: query+bias
    __shared__ float p_lds[NH][NPAD];                    // 2 KB: scores then probs
    __shared__ __align__(16) float wkv_lds[NH][KDIM];    // 1 KB -> total 37376 B

    const int bt   = blockIdx.x;
    const int tid  = threadIdx.x;
    const int h    = tid >> 6;    // wave index == head index
    const int lane = tid & 63;
    const int col  = lane & 15;   // MFMA n/m lane index
    const int quad = lane >> 4;   // MFMA k-group / row-group

    const float* __restrict__ kvg = kv_x + (size_t)bt * NKEY * KDIM;

    // ---- convert kv (global) -> fragment-ordered fp16 LDS + fp16 kv^T ----
    // chunk = nt*2+ks; frag write addr = chunk*1024 + lane*16: lane-linear.
    // Fragment content: kv[nt*16 + (lane&15)][ks*32 + (lane>>4)*8 + j]
    #pragma unroll
    for (int w = 0; w < 4; ++w) {
        const int chunk = w * 4 + h;          // each wave does 4 chunks
        const int nt = chunk >> 1, ks = chunk & 1;
        const int n  = nt * 16 + (lane & 15);
        const int k0 = ks * 32 + (lane >> 4) * 8;
        float4 a = make_float4(0.f, 0.f, 0.f, 0.f);
        float4 b = make_float4(0.f, 0.f, 0.f, 0.f);
        if (n < NKEY) {
            const float* p = kvg + (size_t)n * KDIM + k0;
            a = *(const float4*)p;
            b = *(const float4*)(p + 4);
        }
        half8v hv = cvt8_rne(a, b);
        *(half8v*)&frag[chunk][lane][0] = hv;
        #pragma unroll
        for (int j = 0; j < 8; ++j)           // transpose: rows k0..k0+7, col n
            kvT[k0 + j][n] = hv[j];           // zeros land in column 127
    }

    // ---- query_j + bias -> qb_lds[channel] ----
    {
        const float4* Wq4 = (const float4*)(Wq + (size_t)tid * KDIM);
        const float4* q4g = (const float4*)(q_x + (size_t)bt * KDIM);
        float4 qa = {0.f, 0.f, 0.f, 0.f};
        #pragma unroll
        for (int i = 0; i < 16; ++i) {
            float4 w = Wq4[i];
            float4 q4 = q4g[i];
            qa.x = fmaf(q4.x, w.x, qa.x);
            qa.y = fmaf(q4.y, w.y, qa.y);
            qa.z = fmaf(q4.z, w.z, qa.z);
            qa.w = fmaf(q4.w, w.w, qa.w);
        }
        qb_lds[tid] = (qa.x + qa.y) + (qa.z + qa.w) + bias[tid & 63];
    }

    // ---- A-fragments: Wk rows of this head, fp16 RNE ----
    // A layout: lane holds Wk[h*64 + jt*16 + col][ks*32 + quad*8 + j]
    half8v ah[4][2];
    #pragma unroll
    for (int jt = 0; jt < 4; ++jt)
        #pragma unroll
        for (int ks = 0; ks < 2; ++ks) {
            const float* wrow = Wk + (size_t)(h * 64 + jt * 16 + col) * KDIM
                                   + ks * 32 + quad * 8;
            float4 a = *(const float4*)wrow;
            float4 b = *(const float4*)(wrow + 4);
            ah[jt][ks] = cvt8_rne(a, b);
        }

    __syncthreads();   // barrier: frags + kvT + qb ready

    // ---- per-lane qb / ws for epilogue: j = jt*16 + quad*4 + r ----
    float qbv[4][4], wsv[4][4];
    #pragma unroll
    for (int jt = 0; jt < 4; ++jt)
        #pragma unroll
        for (int r = 0; r < 4; ++r) {
            int j = jt * 16 + quad * 4 + r;
            qbv[jt][r] = qb_lds[h * 64 + j];
            wsv[jt][r] = Ws[j];
        }

    // ---- scores: 8 n-tiles of 16 keys; single-pass fp16 MFMA ----
    #pragma unroll
    for (int nt = 0; nt < 8; ++nt) {
        half8v b0 = *(const half8v*)&frag[nt * 2 + 0][lane][0];
        half8v b1 = *(const half8v*)&frag[nt * 2 + 1][lane][0];

        floatx4 acc[4];
        __builtin_amdgcn_s_setprio(1);        // T5: favor MFMA-issuing wave
        #pragma unroll
        for (int jt = 0; jt < 4; ++jt) {
            floatx4 c = {0.f, 0.f, 0.f, 0.f};
            c = __builtin_amdgcn_mfma_f32_16x16x32_f16(ah[jt][0], b0, c, 0, 0, 0);
            c = __builtin_amdgcn_mfma_f32_16x16x32_f16(ah[jt][1], b1, c, 0, 0, 0);
            acc[jt] = c;
        }
        __builtin_amdgcn_s_setprio(0);

        // epilogue: score[n] = sum_j tanh(key + qb[j]) * ws[j]
        // D layout: col = lane&15 = n in tile, row = quad*4 + r = j in jt
        float partial = 0.f;
        #pragma unroll
        for (int jt = 0; jt < 4; ++jt)
            #pragma unroll
            for (int r = 0; r < 4; ++r)
                partial = fmaf(fast_tanh(acc[jt][r] + qbv[jt][r]), wsv[jt][r], partial);
        partial += __shfl_xor(partial, 16, 64);   // reduce across quads (same col)
        partial += __shfl_xor(partial, 32, 64);
        if (lane < 16) p_lds[h][nt * 16 + lane] = partial;
    }
    // no barrier: wave h is sole writer+reader of p_lds[h][*] (DS in-order)

    // ---- softmax over the 127 real keys (2 scores per lane) ----
    float invl;
    {
        float s_a = p_lds[h][lane];
        float s_b = p_lds[h][64 + lane];
        if (lane == 63) s_b = -1e30f;          // mask pad row 127
        float mx = fmaxf(s_a, s_b);
        #pragma unroll
        for (int off = 32; off > 0; off >>= 1)
            mx = fmaxf(mx, __shfl_xor(mx, off, 64));
        float pa = __expf(s_a - mx);
        float pb = __expf(s_b - mx);           // lane 63 -> 0
        float ls = pa + pb;
        #pragma unroll
        for (int off = 32; off > 0; off >>= 1)
            ls += __shfl_xor(ls, off, 64);
        invl = 1.f / ls;
        p_lds[h][lane]      = pa;              // unnormalized probs
        p_lds[h][64 + lane] = pb;              // p_lds[h][127] = 0 masks pad
    }

    // ---- Phase B: wkv[h][k=lane] = (sum_n p[n] * kvT[k][n]) / l, all LDS ----
    // 32 linear ds_read_b64 of row k (stride 264 B == 2 dw mod 32: lanes
    // k,k+16 alias 2-way = free; k,k+8 differ by 16 banks). Probs: float4
    // uniform broadcast. Column 127 holds zeros; p[127] = 0 too.
    {
        const _Float16* kvr = &kvT[lane][0];
        float w0 = 0.f, w1 = 0.f, w2 = 0.f, w3 = 0.f;
        #pragma unroll 8
        for (int s = 0; s < 32; ++s) {
            half4v v  = *(const half4v*)(kvr + s * 4);
            float4 p4 = *(const float4*)&p_lds[h][s * 4];    // uniform broadcast
            w0 = fmaf(p4.x, (float)v[0], w0);
            w1 = fmaf(p4.y, (float)v[1], w1);
            w2 = fmaf(p4.z, (float)v[2], w2);
            w3 = fmaf(p4.w, (float)v[3], w3);
        }
        wkv_lds[h][lane] = ((w0 + w1) + (w2 + w3)) * invl;
    }
    // no barrier: wkv_lds[h] written and read only by wave h (DS in-order)

    // ---- Phase C: out[j] = wkv[h,:] . Wv[j,:] ----
    {
        const float4* Wv4 = (const float4*)(Wv + (size_t)tid * KDIM);
        const float4* wv_row = (const float4*)wkv_lds[h];
        float4 oa = {0.f, 0.f, 0.f, 0.f};
        #pragma unroll
        for (int i = 0; i < 16; ++i) {
            float4 w = Wv4[i];
            float4 c = wv_row[i];                        // broadcast
            oa.x = fmaf(c.x, w.x, oa.x);
            oa.y = fmaf(c.y, w.y, oa.y);
            oa.z = fmaf(c.z, w.z, oa.z);
            oa.w = fmaf(c.w, w.w, oa.w);
        }
        out[(size_t)bt * CH + tid] = (oa.x + oa.y) + (oa.z + oa.w);
    }
}

extern "C" void kernel_launch(void* const* d_in, const int* in_sizes, int n_in,
                              void* d_out, int out_size, void* d_ws, size_t ws_size,
                              hipStream_t stream) {
    const float* q_x  = (const float*)d_in[0];
    const float* kv_x = (const float*)d_in[1];
    const float* Wk   = (const float*)d_in[2];
    const float* Wq   = (const float*)d_in[3];
    const float* Wv   = (const float*)d_in[4];
    const float* bias = (const float*)d_in[5];
    const float* Ws   = (const float*)d_in[6];
    const float* bs   = (const float*)d_in[7];
    float* out = (float*)d_out;

    attn_kernel<<<dim3(B * T), dim3(256), 0, stream>>>(
        q_x, kv_x, Wk, Wq, Wv, bias, Ws, bs, out);
}

// Round 16
// 112.562 us; speedup vs baseline: 1.0461x; 1.0205x over previous
//
#include <hip/hip_runtime.h>
#include <math.h>

#define B 8
#define T 128
#define NKEY 127   // t-1
#define NPAD 128   // padded key count (score row 127 forced to prob 0)
#define KDIM 64    // Q_DIM == KV_DIM
#define NH 4       // heads
#define CH 256     // NH*KDIM output channels

typedef _Float16 half8v __attribute__((ext_vector_type(8)));  // 8 fp16 (4 VGPRs)
typedef _Float16 half4v __attribute__((ext_vector_type(4)));  // 4 fp16 (b64)
typedef float floatx4 __attribute__((ext_vector_type(4)));    // MFMA C/D

// tanh(x) = 1 - 2/(e^{2x}+1). Saturates correctly at +/-inf, no clamp needed.
__device__ __forceinline__ float fast_tanh(float x) {
    float e = __expf(2.f * x);
    float r = __builtin_amdgcn_rcpf(e + 1.f);
    return fmaf(-2.f, r, 1.f);
}

// 8x float -> fp16 RNE. Verified (R15/R17 pass): absmax <= 9.77e-4.
__device__ __forceinline__ half8v cvt8_rne(const float4& a, const float4& b) {
    half8v h;
    h[0] = (_Float16)a.x; h[1] = (_Float16)a.y;
    h[2] = (_Float16)a.z; h[3] = (_Float16)a.w;
    h[4] = (_Float16)b.x; h[5] = (_Float16)b.y;
    h[6] = (_Float16)b.z; h[7] = (_Float16)b.w;
    return h;
}

// R23 = R17 champion, code size shrunk ~4x. THEORY: instruction-fetch
// starvation. Fully-unrolled text (~3-4K instr ~= 25-30 KB) is evicted from
// L2 AND L3 by the harness's 262 MB inter-iteration fill -> every dispatch,
// every CU streams its whole text from HBM through the scalar front-end;
// straight-line code has no fetch reuse, and a starved front-end shows up in
// NO busy counter. This explains the full falsification ledger (occupancy,
// epilogue VALU, staging latency, score ILP, memory traffic, setprio -- all
// neutral, all left code size unchanged) and the 40-46us invariant.
// Changes are PRAGMA-ONLY vs R17 (no math, no layout):
//   * score nt loop:  unroll 1  (body ~200 instr emitted once, not 8x;
//     register arrays inside keep static indices -- jt/r loops stay unrolled)
//   * Wq pass:        unroll 2  (was 16x)
//   * Phase B:        unroll 4  (was 8x)
//   * Phase C:        unroll 2  (was 16x)
__global__ __launch_bounds__(256, 2)
void attn_kernel(const float* __restrict__ q_x,   // (B,T,64)
                 const float* __restrict__ kv_x,  // (B,T,127,64)
                 const float* __restrict__ Wk,    // (256,64)
                 const float* __restrict__ Wq,    // (256,64)
                 const float* __restrict__ Wv,    // (256,64)
                 const float* __restrict__ bias,  // (64,)
                 const float* __restrict__ Ws,    // (1,64)
                 const float* __restrict__ bs,    // (1,) -- cancels in softmax
                 float* __restrict__ out)         // (B,T,256)
{
    __shared__ __align__(16) _Float16 frag[16][64][8];   // 16 KB: fp16 B-frags
    __shared__ __align__(16) _Float16 kvT[64][132];      // 16.5 KB: fp16 kv^T
    __shared__ float qb_lds[CH];                         // 1 KB: query+bias
    __shared__ float p_lds[NH][NPAD];                    // 2 KB: scores then probs
    __shared__ __align__(16) float wkv_lds[NH][KDIM];    // 1 KB -> total 37376 B

    const int bt   = blockIdx.x;
    const int tid  = threadIdx.x;
    const int h    = tid >> 6;    // wave index == head index
    const int lane = tid & 63;
    const int col  = lane & 15;   // MFMA n/m lane index
    const int quad = lane >> 4;   // MFMA k-group / row-group

    const float* __restrict__ kvg = kv_x + (size_t)bt * NKEY * KDIM;

    // ---- convert kv (global) -> fragment-ordered fp16 LDS + fp16 kv^T ----
    // chunk = nt*2+ks; frag write addr = chunk*1024 + lane*16: lane-linear.
    // Fragment content: kv[nt*16 + (lane&15)][ks*32 + (lane>>4)*8 + j]
    #pragma unroll
    for (int w = 0; w < 4; ++w) {
        const int chunk = w * 4 + h;          // each wave does 4 chunks
        const int nt = chunk >> 1, ks = chunk & 1;
        const int n  = nt * 16 + (lane & 15);
        const int k0 = ks * 32 + (lane >> 4) * 8;
        float4 a = make_float4(0.f, 0.f, 0.f, 0.f);
        float4 b = make_float4(0.f, 0.f, 0.f, 0.f);
        if (n < NKEY) {
            const float* p = kvg + (size_t)n * KDIM + k0;
            a = *(const float4*)p;
            b = *(const float4*)(p + 4);
        }
        half8v hv = cvt8_rne(a, b);
        *(half8v*)&frag[chunk][lane][0] = hv;
        #pragma unroll
        for (int j = 0; j < 8; ++j)           // transpose: rows k0..k0+7, col n
            kvT[k0 + j][n] = hv[j];           // zeros land in column 127
    }

    // ---- query_j + bias -> qb_lds[channel] ----
    {
        const float4* Wq4 = (const float4*)(Wq + (size_t)tid * KDIM);
        const float4* q4g = (const float4*)(q_x + (size_t)bt * KDIM);
        float4 qa = {0.f, 0.f, 0.f, 0.f};
        #pragma unroll 2
        for (int i = 0; i < 16; ++i) {
            float4 w = Wq4[i];
            float4 q4 = q4g[i];
            qa.x = fmaf(q4.x, w.x, qa.x);
            qa.y = fmaf(q4.y, w.y, qa.y);
            qa.z = fmaf(q4.z, w.z, qa.z);
            qa.w = fmaf(q4.w, w.w, qa.w);
        }
        qb_lds[tid] = (qa.x + qa.y) + (qa.z + qa.w) + bias[tid & 63];
    }

    // ---- A-fragments: Wk rows of this head, fp16 RNE ----
    // A layout: lane holds Wk[h*64 + jt*16 + col][ks*32 + quad*8 + j]
    half8v ah[4][2];
    #pragma unroll
    for (int jt = 0; jt < 4; ++jt)
        #pragma unroll
        for (int ks = 0; ks < 2; ++ks) {
            const float* wrow = Wk + (size_t)(h * 64 + jt * 16 + col) * KDIM
                                   + ks * 32 + quad * 8;
            float4 a = *(const float4*)wrow;
            float4 b = *(const float4*)(wrow + 4);
            ah[jt][ks] = cvt8_rne(a, b);
        }

    __syncthreads();   // barrier: frags + kvT + qb ready

    // ---- per-lane qb / ws for epilogue: j = jt*16 + quad*4 + r ----
    float qbv[4][4], wsv[4][4];
    #pragma unroll
    for (int jt = 0; jt < 4; ++jt)
        #pragma unroll
        for (int r = 0; r < 4; ++r) {
            int j = jt * 16 + quad * 4 + r;
            qbv[jt][r] = qb_lds[h * 64 + j];
            wsv[jt][r] = Ws[j];
        }

    // ---- scores: 8 n-tiles of 16 keys; single-pass fp16 MFMA ----
    // unroll 1: body emitted ONCE (~200 instr, was 8x). All register arrays
    // inside use static indices (jt/r loops unrolled); nt only feeds LDS addrs.
    #pragma unroll 1
    for (int nt = 0; nt < 8; ++nt) {
        half8v b0 = *(const half8v*)&frag[nt * 2 + 0][lane][0];
        half8v b1 = *(const half8v*)&frag[nt * 2 + 1][lane][0];

        floatx4 acc[4];
        #pragma unroll
        for (int jt = 0; jt < 4; ++jt) {
            floatx4 c = {0.f, 0.f, 0.f, 0.f};
            c = __builtin_amdgcn_mfma_f32_16x16x32_f16(ah[jt][0], b0, c, 0, 0, 0);
            c = __builtin_amdgcn_mfma_f32_16x16x32_f16(ah[jt][1], b1, c, 0, 0, 0);
            acc[jt] = c;
        }

        // epilogue: score[n] = sum_j tanh(key + qb[j]) * ws[j]
        // D layout: col = lane&15 = n in tile, row = quad*4 + r = j in jt
        float partial = 0.f;
        #pragma unroll
        for (int jt = 0; jt < 4; ++jt)
            #pragma unroll
            for (int r = 0; r < 4; ++r)
                partial = fmaf(fast_tanh(acc[jt][r] + qbv[jt][r]), wsv[jt][r], partial);
        partial += __shfl_xor(partial, 16, 64);   // reduce across quads (same col)
        partial += __shfl_xor(partial, 32, 64);
        if (lane < 16) p_lds[h][nt * 16 + lane] = partial;
    }
    // no barrier: wave h is sole writer+reader of p_lds[h][*] (DS in-order)

    // ---- softmax over the 127 real keys (2 scores per lane) ----
    float invl;
    {
        float s_a = p_lds[h][lane];
        float s_b = p_lds[h][64 + lane];
        if (lane == 63) s_b = -1e30f;          // mask pad row 127
        float mx = fmaxf(s_a, s_b);
        #pragma unroll
        for (int off = 32; off > 0; off >>= 1)
            mx = fmaxf(mx, __shfl_xor(mx, off, 64));
        float pa = __expf(s_a - mx);
        float pb = __expf(s_b - mx);           // lane 63 -> 0
        float ls = pa + pb;
        #pragma unroll
        for (int off = 32; off > 0; off >>= 1)
            ls += __shfl_xor(ls, off, 64);
        invl = 1.f / ls;
        p_lds[h][lane]      = pa;              // unnormalized probs
        p_lds[h][64 + lane] = pb;              // p_lds[h][127] = 0 masks pad
    }

    // ---- Phase B: wkv[h][k=lane] = (sum_n p[n] * kvT[k][n]) / l, all LDS ----
    // 32 linear ds_read_b64 of row k (stride 264 B == 2 dw mod 32: lanes
    // k,k+16 alias 2-way = free; k,k+8 differ by 16 banks). Probs: float4
    // uniform broadcast. Column 127 holds zeros; p[127] = 0 too.
    {
        const _Float16* kvr = &kvT[lane][0];
        float w0 = 0.f, w1 = 0.f, w2 = 0.f, w3 = 0.f;
        #pragma unroll 4
        for (int s = 0; s < 32; ++s) {
            half4v v  = *(const half4v*)(kvr + s * 4);
            float4 p4 = *(const float4*)&p_lds[h][s * 4];    // uniform broadcast
            w0 = fmaf(p4.x, (float)v[0], w0);
            w1 = fmaf(p4.y, (float)v[1], w1);
            w2 = fmaf(p4.z, (float)v[2], w2);
            w3 = fmaf(p4.w, (float)v[3], w3);
        }
        wkv_lds[h][lane] = ((w0 + w1) + (w2 + w3)) * invl;
    }
    // no barrier: wkv_lds[h] written and read only by wave h (DS in-order)

    // ---- Phase C: out[j] = wkv[h,:] . Wv[j,:] ----
    {
        const float4* Wv4 = (const float4*)(Wv + (size_t)tid * KDIM);
        const float4* wv_row = (const float4*)wkv_lds[h];
        float4 oa = {0.f, 0.f, 0.f, 0.f};
        #pragma unroll 2
        for (int i = 0; i < 16; ++i) {
            float4 w = Wv4[i];
            float4 c = wv_row[i];                        // broadcast
            oa.x = fmaf(c.x, w.x, oa.x);
            oa.y = fmaf(c.y, w.y, oa.y);
            oa.z = fmaf(c.z, w.z, oa.z);
            oa.w = fmaf(c.w, w.w, oa.w);
        }
        out[(size_t)bt * CH + tid] = (oa.x + oa.y) + (oa.z + oa.w);
    }
}

extern "C" void kernel_launch(void* const* d_in, const int* in_sizes, int n_in,
                              void* d_out, int out_size, void* d_ws, size_t ws_size,
                              hipStream_t stream) {
    const float* q_x  = (const float*)d_in[0];
    const float* kv_x = (const float*)d_in[1];
    const float* Wk   = (const float*)d_in[2];
    const float* Wq   = (const float*)d_in[3];
    const float* Wv   = (const float*)d_in[4];
    const float* bias = (const float*)d_in[5];
    const float* Ws   = (const float*)d_in[6];
    const float* bs   = (const float*)d_in[7];
    float* out = (float*)d_out;

    attn_kernel<<<dim3(B * T), dim3(256), 0, stream>>>(
        q_x, kv_x, Wk, Wq, Wv, bias, Ws, bs, out);
}